// Round 10
// baseline (451.416 us; speedup 1.0000x reference)
//
#include <hip/hip_runtime.h>

#define NS 512
#define DF 512
#define NQ 16384

// ws layout (float offsets)
#define WS_MEAN0 0
#define WS_MEAN1 512
#define WS_MEANA 1024
#define WS_CNT   1536
#define WS_V0    2048
#define WS_V1    2560
#define WS_KC    3072
#define WS_M     4096                      // A0: M / P fp32 [2][512][512]
#define WS_PB    (WS_M + 2*DF*DF)          // P bf16 [2][512][512] (as ushort)
#define WS_A1    (WS_PB + DF*DF)           // A1: ping-pong fp32 [2][512][512]
#define WS_QB    (WS_A1 + 2*DF*DF)         // Q bf16 [16384][512] (ushort)
#define WS_GP    WS_QB                     // Gram partials [8][2][512][512] f32 (consumed before QB written)

typedef __attribute__((ext_vector_type(8))) short short8;
typedef __attribute__((ext_vector_type(4))) float floatx4;

__device__ __forceinline__ unsigned short f2bf(float f) {
    unsigned u = __float_as_uint(f);
    unsigned r = (u + 0x7fffu + ((u >> 16) & 1u)) >> 16;
    return (unsigned short)r;
}

__device__ __forceinline__ void load_lds16(const void* g, void* l) {
    __builtin_amdgcn_global_load_lds(
        (const __attribute__((address_space(1))) unsigned int*)g,
        (__attribute__((address_space(3))) unsigned int*)l, 16, 0, 0);
}

// ---------------- K1: class stats (8 blocks x 512 thr) ----------------
__global__ __launch_bounds__(512) void k_stats(const float* __restrict__ S,
                                               const int* __restrict__ lab,
                                               float* __restrict__ ws) {
    __shared__ int lb[NS];
    __shared__ float r0[8][64], r1[8][64];
    __shared__ int rc[8];
    int tid = threadIdx.x;
    for (int l = tid; l < NS; l += 512) lb[l] = lab[l];
    __syncthreads();
    int dl = tid & 63, ch = tid >> 6;          // ch 0..7
    int dd = blockIdx.x * 64 + dl;
    float s0 = 0.f, s1 = 0.f;
    int n1 = 0;
    for (int n = ch * 64; n < ch * 64 + 64; ++n) {
        float v = S[n * DF + dd];
        if (lb[n]) { s1 += v; n1++; } else { s0 += v; }
    }
    r0[ch][dl] = s0; r1[ch][dl] = s1;
    if (dl == 0) rc[ch] = n1;
    __syncthreads();
    if (ch == 0) {
        float t0 = 0.f, t1 = 0.f; int n1t = 0;
#pragma unroll
        for (int x = 0; x < 8; ++x) { t0 += r0[x][dl]; t1 += r1[x][dl]; n1t += rc[x]; }
        float fn1 = (float)n1t, fn0 = (float)(NS - n1t);
        ws[WS_MEAN0 + dd] = t0 / fn0;
        ws[WS_MEAN1 + dd] = t1 / fn1;
        ws[WS_MEANA + dd] = (t0 + t1) / (float)NS;
        if (blockIdx.x == 0 && dl == 0) {
            ws[WS_CNT] = fn0; ws[WS_CNT + 1] = fn1;
            ws[WS_KC] = 0.f; ws[WS_KC + 1] = 0.f;
        }
    }
}

// ---------------- K2a: masked partial Grams (K-split x8) ----------------
__global__ __launch_bounds__(256) void k_gram_part(const float* __restrict__ S,
                                                   const int* __restrict__ lab,
                                                   float* __restrict__ ws) {
    __shared__ float SA[16 * 65];
    __shared__ float SB[16 * 65];
    __shared__ int lb[16];
    int tx = threadIdx.x, ty = threadIdx.y;
    int tid = ty * 16 + tx;
    int i0 = blockIdx.x * 64, j0 = blockIdx.y * 64;
    int z = blockIdx.z;
    float a0[4][4] = {{0.f}}, a1[4][4] = {{0.f}};
    for (int nc = z * 64; nc < z * 64 + 64; nc += 16) {
#pragma unroll
        for (int l = 0; l < 4; ++l) {
            int idx = tid + 256 * l;
            int nn = idx >> 6, col = idx & 63;
            SA[nn * 65 + col] = S[(nc + nn) * DF + i0 + col];
            SB[nn * 65 + col] = S[(nc + nn) * DF + j0 + col];
        }
        if (tid < 16) lb[tid] = lab[nc + tid];
        __syncthreads();
#pragma unroll
        for (int kk = 0; kk < 16; ++kk) {
            float av[4], bv[4];
#pragma unroll
            for (int r = 0; r < 4; ++r) av[r] = SA[kk * 65 + ty * 4 + r];
#pragma unroll
            for (int s = 0; s < 4; ++s) bv[s] = SB[kk * 65 + tx * 4 + s];
            if (lb[kk]) {
#pragma unroll
                for (int r = 0; r < 4; ++r)
#pragma unroll
                    for (int s = 0; s < 4; ++s) a1[r][s] += av[r] * bv[s];
            } else {
#pragma unroll
                for (int r = 0; r < 4; ++r)
#pragma unroll
                    for (int s = 0; s < 4; ++s) a0[r][s] += av[r] * bv[s];
            }
        }
        __syncthreads();
    }
    float* Gp = ws + WS_GP;
#pragma unroll
    for (int r = 0; r < 4; ++r) {
        int i = i0 + ty * 4 + r;
#pragma unroll
        for (int s = 0; s < 4; ++s) {
            int j = j0 + tx * 4 + s;
            Gp[((z * 2 + 0) * DF + i) * DF + j] = a0[r][s];
            Gp[((z * 2 + 1) * DF + i) * DF + j] = a1[r][s];
        }
    }
}

// ---------------- K2b: assemble M_c from partials (into A0) ----------------
__global__ __launch_bounds__(256) void k_asm(float* __restrict__ ws) {
    const float* Gp = ws + WS_GP;
    int e = blockIdx.x * 256 + threadIdx.x;   // 0..262143
    int i = e >> 9, j = e & 511;
    float g0 = 0.f, g1 = 0.f;
#pragma unroll
    for (int ch = 0; ch < 8; ++ch) {
        g0 += Gp[((ch * 2 + 0) * DF + i) * DF + j];
        g1 += Gp[((ch * 2 + 1) * DF + i) * DF + j];
    }
    float n0 = ws[WS_CNT], n1 = ws[WS_CNT + 1];
    float lam0 = fminf(n0 / (n0 + 1.f), 0.1f);
    float lam1 = fminf(n1 / (n1 + 1.f), 0.1f);
    float m0i = ws[WS_MEAN0 + i], m1i = ws[WS_MEAN1 + i], mai = ws[WS_MEANA + i];
    float m0j = ws[WS_MEAN0 + j], m1j = ws[WS_MEAN1 + j], maj = ws[WS_MEANA + j];
    float task = (g0 + g1 - (float)NS * mai * maj) / (float)(NS - 1);
    float cov0 = (g0 - n0 * m0i * m0j) / (n0 - 1.f);
    float cov1 = (g1 - n1 * m1i * m1j) / (n1 - 1.f);
    float dg = (i == j) ? 0.1f : 0.f;
    ws[WS_M + i * DF + j] = lam0 * cov0 + (1.f - lam0) * task + dg;
    ws[WS_M + DF * DF + i * DF + j] = lam1 * cov1 + (1.f - lam1) * task + dg;
}

// ---------------- K3: fused Gauss-Jordan step (src -> dst ping-pong) ----------------
// grid (64 tiles, 2 classes, 2 col-halves) = 256 blocks. Every block
// redundantly inverts the 64x64 pivot in LDS (4-pivot rounds, round loop
// pinned with unroll 1 -- the compiler's auto-unroll of constant-trip loops
// caused the R6-R8 256-VGPR scratch stalls), then applies its col-half tile
// update reading ONLY src, writing ONLY dst -> zero cross-block dependency.
__global__ __launch_bounds__(256) void k_step(float* __restrict__ ws, int k,
                                              int so, int dofs, int wbf) {
    int c = blockIdx.y;
    int jh = blockIdx.z;
    int ti = blockIdx.x >> 3, tj = blockIdx.x & 7;
    const float* S_ = ws + so + (size_t)c * DF * DF;
    float* D_ = ws + dofs + (size_t)c * DF * DF;
    unsigned short* pb = (unsigned short*)(ws + WS_PB) + (size_t)c * DF * DF;
    __shared__ float T[64 * 65];
    __shared__ float LV[64 * 65];
    __shared__ float LU[64 * 33];
    __shared__ float D1[64 * 33];
    int tid = threadIdx.x;
    int jl = tid & 63, w = tid >> 6;
    bool isdiag = (ti == k) && (tj == k);
    bool isrow = (ti == k) && (tj != k);
    bool iscol = (tj == k) && (ti != k);

    // phase 0: global reads (all from src)
    {
        const float* Akk = S_ + (k * 64) * DF + k * 64;
#pragma unroll
        for (int m = 0; m < 16; ++m) {
            int idx = tid + 256 * m;
            int i = idx >> 6, j = idx & 63;
            T[i * 65 + j] = Akk[i * DF + j];
        }
    }
    if (ti != k) {
        const float* src = S_ + (ti * 64) * DF + k * 64;   // V = A[ti][k] (full)
#pragma unroll
        for (int m = 0; m < 16; ++m) {
            int idx = tid + 256 * m;
            int i = idx >> 6, j = idx & 63;
            LV[i * 65 + j] = src[i * DF + j];
        }
    }
    if (tj != k) {
        const float* src = S_ + (k * 64) * DF + tj * 64 + jh * 32;  // U half-cols
#pragma unroll
        for (int m = 0; m < 8; ++m) {
            int idx = tid + 256 * m;
            int i = idx >> 5, j = idx & 31;
            LU[i * 33 + j] = src[i * DF + j];
        }
    }
    __syncthreads();

    // phase 1: 4 pivots per round, 16 rounds, 2 barriers/round (unroll 1!)
#pragma unroll 1
    for (int r = 0; r < 16; ++r) {
        int q0 = r * 4;
        float B[4][4];
#pragma unroll
        for (int a = 0; a < 4; ++a)
#pragma unroll
            for (int b = 0; b < 4; ++b) B[a][b] = T[(q0 + a) * 65 + q0 + b];
#pragma unroll
        for (int p = 0; p < 4; ++p) {
            float piv = 1.0f / B[p][p];
#pragma unroll
            for (int j = 0; j < 4; ++j) if (j != p) B[p][j] *= piv;
#pragma unroll
            for (int i2 = 0; i2 < 4; ++i2) if (i2 != p) {
                float f = B[i2][p];
#pragma unroll
                for (int j = 0; j < 4; ++j) if (j != p) B[i2][j] -= f * B[p][j];
                B[i2][p] = -f * piv;
            }
            B[p][p] = piv;
        }
        float Rv0 = T[(q0 + 0) * 65 + jl];
        float Rv1 = T[(q0 + 1) * 65 + jl];
        float Rv2 = T[(q0 + 2) * 65 + jl];
        float Rv3 = T[(q0 + 3) * 65 + jl];
        float nr[4];
#pragma unroll
        for (int a = 0; a < 4; ++a)
            nr[a] = B[a][0] * Rv0 + B[a][1] * Rv1 + B[a][2] * Rv2 + B[a][3] * Rv3;
        int bsel = jl - q0;
        bool colin = (unsigned)bsel < 4u;
        float Bc[4];
#pragma unroll
        for (int a = 0; a < 4; ++a)
            Bc[a] = (bsel == 0) ? B[a][0] : (bsel == 1) ? B[a][1]
                  : (bsel == 2) ? B[a][2] : B[a][3];
        float nv[16];
#pragma unroll
        for (int m = 0; m < 16; ++m) {
            int i = w * 16 + m;   // wave-uniform -> broadcast LDS reads
            float c0 = T[i * 65 + q0 + 0];
            float c1 = T[i * 65 + q0 + 1];
            float c2 = T[i * 65 + q0 + 2];
            float c3 = T[i * 65 + q0 + 3];
            float tv = T[i * 65 + jl];
            float g = tv - (c0 * nr[0] + c1 * nr[1] + c2 * nr[2] + c3 * nr[3]);
            int rsel = i - q0;
            bool rowin = (unsigned)rsel < 4u;
            if (rowin)
                g = (rsel == 0) ? nr[0] : (rsel == 1) ? nr[1]
                  : (rsel == 2) ? nr[2] : nr[3];
            if (colin) {
                float gc;
                if (rowin)
                    gc = (rsel == 0) ? Bc[0] : (rsel == 1) ? Bc[1]
                       : (rsel == 2) ? Bc[2] : Bc[3];
                else
                    gc = -(c0 * Bc[0] + c1 * Bc[1] + c2 * Bc[2] + c3 * Bc[3]);
                g = gc;
            }
            nv[m] = g;
        }
        __syncthreads();
#pragma unroll
        for (int m = 0; m < 16; ++m) T[(w * 16 + m) * 65 + jl] = nv[m];
        __syncthreads();
    }

    // phase 2: col-half tile update (read src, write dst)
    int tx8 = tid & 7, ty32 = tid >> 3;
    int cb0 = jh * 32;
    if (isdiag) {
        float* dst = D_ + (k * 64) * DF + k * 64;
#pragma unroll
        for (int m = 0; m < 8; ++m) {
            int idx = tid + 256 * m;
            int i = idx >> 5, j = idx & 31;
            float v = T[i * 65 + cb0 + j];
            dst[i * DF + cb0 + j] = v;
            if (wbf) pb[(size_t)(k * 64 + i) * DF + k * 64 + cb0 + j] = f2bf(v);
        }
    } else if (isrow) {
        float acc[2][4] = {{0.f}};
#pragma unroll 4
        for (int kk = 0; kk < 64; ++kk) {
            float av[2], bv[4];
#pragma unroll
            for (int r = 0; r < 2; ++r) av[r] = T[(ty32 * 2 + r) * 65 + kk];
#pragma unroll
            for (int s = 0; s < 4; ++s) bv[s] = LU[kk * 33 + tx8 * 4 + s];
#pragma unroll
            for (int r = 0; r < 2; ++r)
#pragma unroll
                for (int s = 0; s < 4; ++s) acc[r][s] += av[r] * bv[s];
        }
        float* dst = D_ + (k * 64) * DF + tj * 64 + cb0;
#pragma unroll
        for (int r = 0; r < 2; ++r)
#pragma unroll
            for (int s = 0; s < 4; ++s) {
                float v = acc[r][s];
                dst[(ty32 * 2 + r) * DF + tx8 * 4 + s] = v;
                if (wbf) pb[(size_t)(k * 64 + ty32 * 2 + r) * DF + tj * 64 + cb0 + tx8 * 4 + s] = f2bf(v);
            }
    } else if (iscol) {
        float acc[2][4] = {{0.f}};
#pragma unroll 4
        for (int kk = 0; kk < 64; ++kk) {
            float av[2], bv[4];
#pragma unroll
            for (int r = 0; r < 2; ++r) av[r] = LV[(ty32 * 2 + r) * 65 + kk];
#pragma unroll
            for (int s = 0; s < 4; ++s) bv[s] = T[kk * 65 + cb0 + tx8 * 4 + s];
#pragma unroll
            for (int r = 0; r < 2; ++r)
#pragma unroll
                for (int s = 0; s < 4; ++s) acc[r][s] += av[r] * bv[s];
        }
        float* dst = D_ + (ti * 64) * DF + k * 64 + cb0;
#pragma unroll
        for (int r = 0; r < 2; ++r)
#pragma unroll
            for (int s = 0; s < 4; ++s) {
                float v = -acc[r][s];
                dst[(ty32 * 2 + r) * DF + tx8 * 4 + s] = v;
                if (wbf) pb[(size_t)(ti * 64 + ty32 * 2 + r) * DF + k * 64 + cb0 + tx8 * 4 + s] = f2bf(v);
            }
    } else {
        // interior: out = Y_half - V*(P*U_half)
        float a1[2][4] = {{0.f}};
#pragma unroll 4
        for (int kk = 0; kk < 64; ++kk) {
            float av[2], bv[4];
#pragma unroll
            for (int r = 0; r < 2; ++r) av[r] = T[(ty32 * 2 + r) * 65 + kk];
#pragma unroll
            for (int s = 0; s < 4; ++s) bv[s] = LU[kk * 33 + tx8 * 4 + s];
#pragma unroll
            for (int r = 0; r < 2; ++r)
#pragma unroll
                for (int s = 0; s < 4; ++s) a1[r][s] += av[r] * bv[s];
        }
        __syncthreads();
#pragma unroll
        for (int r = 0; r < 2; ++r)
#pragma unroll
            for (int s = 0; s < 4; ++s) D1[(ty32 * 2 + r) * 33 + tx8 * 4 + s] = a1[r][s];
        __syncthreads();
        float a2[2][4] = {{0.f}};
#pragma unroll 4
        for (int kk = 0; kk < 64; ++kk) {
            float av[2], bv[4];
#pragma unroll
            for (int r = 0; r < 2; ++r) av[r] = LV[(ty32 * 2 + r) * 65 + kk];
#pragma unroll
            for (int s = 0; s < 4; ++s) bv[s] = D1[kk * 33 + tx8 * 4 + s];
#pragma unroll
            for (int r = 0; r < 2; ++r)
#pragma unroll
                for (int s = 0; s < 4; ++s) a2[r][s] += av[r] * bv[s];
        }
        const float* Ys = S_ + (ti * 64) * DF + tj * 64 + cb0;
        float* dst = D_ + (ti * 64) * DF + tj * 64 + cb0;
#pragma unroll
        for (int r = 0; r < 2; ++r)
#pragma unroll
            for (int s = 0; s < 4; ++s) {
                int off = (ty32 * 2 + r) * DF + tx8 * 4 + s;
                float nv2 = Ys[off] - a2[r][s];
                dst[off] = nv2;
                if (wbf) pb[(size_t)(ti * 64 + ty32 * 2 + r) * DF + tj * 64 + cb0 + tx8 * 4 + s] = f2bf(nv2);
            }
    }
}

// ---------------- K4: v_c = P_c m_c, k_c = m^T v ----------------
__global__ __launch_bounds__(256) void k_vk(float* __restrict__ ws) {
    int c = blockIdx.x >> 3, rb = blockIdx.x & 7;
    const float* P = ws + WS_M + c * DF * DF;
    const float* mc = ws + (c ? WS_MEAN1 : WS_MEAN0);
    float* v = ws + (c ? WS_V1 : WS_V0);
    __shared__ float ml[DF];
    __shared__ float red[4][64];
    int tid = threadIdx.x;
    for (int l = tid; l < DF; l += 256) ml[l] = mc[l];
    __syncthreads();
    int rl = tid & 63, ch = tid >> 6;
    int row = rb * 64 + rl;
    float dot = 0.f;
    const float* pr = P + (size_t)row * DF + ch * 128;
#pragma unroll 4
    for (int t = 0; t < 32; ++t) {
        float4 pv = *(const float4*)(pr + t * 4);
        const float* mm = ml + ch * 128 + t * 4;
        dot += pv.x * mm[0] + pv.y * mm[1] + pv.z * mm[2] + pv.w * mm[3];
    }
    red[ch][rl] = dot;
    __syncthreads();
    if (ch == 0) {
        float d = red[0][rl] + red[1][rl] + red[2][rl] + red[3][rl];
        v[row] = d;
        float kp = d * ml[row];
#pragma unroll
        for (int off = 32; off > 0; off >>= 1) kp += __shfl_down(kp, off);
        if (rl == 0) atomicAdd(&ws[WS_KC + c], kp);
    }
}

// ---------------- K5: fused Q->bf16 + logits init ----------------
__global__ __launch_bounds__(256) void k_qinit(const float* __restrict__ Q,
                                               float* __restrict__ ws,
                                               float* __restrict__ out) {
    unsigned short* qbw = (unsigned short*)(ws + WS_QB);
    const float* v0 = ws + WS_V0;
    const float* v1 = ws + WS_V1;
    int lane = threadIdx.x & 63;
    int q = blockIdx.x * 4 + (threadIdx.x >> 6);
    const float* qrow = Q + (size_t)q * DF + lane * 8;
    float4 x0 = *(const float4*)(qrow);
    float4 x1 = *(const float4*)(qrow + 4);
    const float* v0p = v0 + lane * 8;
    const float* v1p = v1 + lane * 8;
    float4 w00 = *(const float4*)(v0p), w01 = *(const float4*)(v0p + 4);
    float4 w10 = *(const float4*)(v1p), w11 = *(const float4*)(v1p + 4);
    float a0 = x0.x * w00.x + x0.y * w00.y + x0.z * w00.z + x0.w * w00.w
             + x1.x * w01.x + x1.y * w01.y + x1.z * w01.z + x1.w * w01.w;
    float a1 = x0.x * w10.x + x0.y * w10.y + x0.z * w10.z + x0.w * w10.w
             + x1.x * w11.x + x1.y * w11.y + x1.z * w11.z + x1.w * w11.w;
    short8 r;
    r[0] = (short)f2bf(x0.x); r[1] = (short)f2bf(x0.y);
    r[2] = (short)f2bf(x0.z); r[3] = (short)f2bf(x0.w);
    r[4] = (short)f2bf(x1.x); r[5] = (short)f2bf(x1.y);
    r[6] = (short)f2bf(x1.z); r[7] = (short)f2bf(x1.w);
    *(short8*)(qbw + (size_t)q * DF + lane * 8) = r;
#pragma unroll
    for (int off = 32; off > 0; off >>= 1) {
        a0 += __shfl_down(a0, off);
        a1 += __shfl_down(a1, off);
    }
    if (lane == 0) {
        out[q * 2 + 0] = 2.f * a0 - ws[WS_KC + 0];
        out[q * 2 + 1] = 2.f * a1 - ws[WS_KC + 1];
    }
}

// ---------------- K6: MFMA GEMM, 128x128 tile, LDS staging + swizzle ----------------
__global__ __launch_bounds__(256, 3) void k_gemm(const float* __restrict__ ws,
                                                 float* __restrict__ out) {
    const unsigned short* qb = (const unsigned short*)(ws + WS_QB);
    int c = blockIdx.y >> 2;
    int n0 = (blockIdx.y & 3) * 128;
    const unsigned short* pbc = (const unsigned short*)(ws + WS_PB) + (size_t)c * DF * DF;
    int q0 = blockIdx.x * 128;
    __shared__ __align__(16) unsigned short Abuf[128 * 64];   // 16 KB
    __shared__ __align__(16) unsigned short Bbuf[128 * 64];   // 16 KB
    int tid = threadIdx.x;
    int w = tid >> 6, lane = tid & 63;
    int quad = lane >> 4, l15 = lane & 15;
    floatx4 acc[2][8];
#pragma unroll
    for (int mt = 0; mt < 2; ++mt)
#pragma unroll
        for (int nt = 0; nt < 8; ++nt) acc[mt][nt] = (floatx4)(0.f);

    for (int kt = 0; kt < 8; ++kt) {
        int kc = kt * 64;
#pragma unroll
        for (int i = 0; i < 4; ++i) {
            int o = tid * 16 + i * 4096;
            int row = o >> 7;
            int sg = ((o >> 4) & 7) ^ (row & 7);
            load_lds16(qb + (size_t)(q0 + row) * DF + kc + sg * 8, (char*)Abuf + o);
        }
#pragma unroll
        for (int i = 0; i < 4; ++i) {
            int o = tid * 16 + i * 4096;
            int row = o >> 7;
            int sg = ((o >> 4) & 7) ^ (row & 7);
            load_lds16(pbc + (size_t)(n0 + row) * DF + kc + sg * 8, (char*)Bbuf + o);
        }
        __syncthreads();
#pragma unroll
        for (int kk2 = 0; kk2 < 2; ++kk2) {
            int u = ((kk2 * 4 + quad) ^ (l15 & 7)) << 4;
            short8 b[8];
#pragma unroll
            for (int nt = 0; nt < 8; ++nt)
                b[nt] = *(const short8*)((const char*)Bbuf + (nt * 16 + l15) * 128 + u);
#pragma unroll
            for (int mt = 0; mt < 2; ++mt) {
                short8 a = *(const short8*)((const char*)Abuf + (w * 32 + mt * 16 + l15) * 128 + u);
#pragma unroll
                for (int nt = 0; nt < 8; ++nt)
                    acc[mt][nt] = __builtin_amdgcn_mfma_f32_16x16x32_bf16(a, b[nt], acc[mt][nt], 0, 0, 0);
            }
        }
        __syncthreads();
    }
#pragma unroll
    for (int mt = 0; mt < 2; ++mt)
#pragma unroll
        for (int reg = 0; reg < 4; ++reg) {
            int row = w * 32 + mt * 16 + quad * 4 + reg;
            float part = 0.f;
#pragma unroll
            for (int nt = 0; nt < 8; ++nt) {
                float h = acc[mt][nt][reg];
                unsigned qu = qb[(size_t)(q0 + row) * DF + n0 + nt * 16 + l15];
                part += h * __uint_as_float(qu << 16);
            }
            part += __shfl_xor(part, 1);
            part += __shfl_xor(part, 2);
            part += __shfl_xor(part, 4);
            part += __shfl_xor(part, 8);
            if (l15 == 0) atomicAdd(&out[(size_t)(q0 + row) * 2 + c], -part);
        }
}

extern "C" void kernel_launch(void* const* d_in, const int* in_sizes, int n_in,
                              void* d_out, int out_size, void* d_ws, size_t ws_size,
                              hipStream_t stream) {
    const float* S = (const float*)d_in[0];
    const int* lab = (const int*)d_in[1];
    const float* Q = (const float*)d_in[2];
    float* out = (float*)d_out;
    float* ws = (float*)d_ws;

    k_stats<<<8, 512, 0, stream>>>(S, lab, ws);
    k_gram_part<<<dim3(8, 8, 8), dim3(16, 16), 0, stream>>>(S, lab, ws);
    k_asm<<<1024, 256, 0, stream>>>(ws);
    int so = WS_M, dofs = WS_A1;
    for (int k = 0; k < 8; ++k) {
        k_step<<<dim3(64, 2, 2), 256, 0, stream>>>(ws, k, so, dofs, k == 7 ? 1 : 0);
        int t = so; so = dofs; dofs = t;
    }
    // after 8 swaps the final matrix lands back in WS_M
    k_vk<<<16, 256, 0, stream>>>(ws);
    k_qinit<<<NQ / 4, 256, 0, stream>>>(Q, ws, out);
    k_gemm<<<dim3(NQ / 128, 8), 256, 0, stream>>>(ws, out);
}

// Round 11
// 444.378 us; speedup vs baseline: 1.0158x; 1.0158x over previous
//
#include <hip/hip_runtime.h>

#define NS 512
#define DF 512
#define NQ 16384

// ws layout (float offsets)
#define WS_MEAN0 0
#define WS_MEAN1 512
#define WS_MEANA 1024
#define WS_CNT   1536
#define WS_V0    2048
#define WS_V1    2560
#define WS_KC    3072
#define WS_M     4096                      // A0: M / P fp32 [2][512][512]
#define WS_PB    (WS_M + 2*DF*DF)          // P bf16 [2][512][512] (as ushort)
#define WS_A1    (WS_PB + DF*DF)           // A1: ping-pong fp32 [2][512][512]
#define WS_QB    (WS_A1 + 2*DF*DF)         // Q bf16 [16384][512] (ushort)
#define WS_GP    WS_QB                     // Gram partials [8][2][512][512] f32 (consumed before QB written)

typedef __attribute__((ext_vector_type(8))) short short8;
typedef __attribute__((ext_vector_type(4))) float floatx4;

__device__ __forceinline__ unsigned short f2bf(float f) {
    unsigned u = __float_as_uint(f);
    unsigned r = (u + 0x7fffu + ((u >> 16) & 1u)) >> 16;
    return (unsigned short)r;
}

// readlane for float: raw builtin takes i32 -> passing float VALUE-converts
// (truncates!). Bitcast explicitly (R5 bug). Lane index may be a runtime
// wave-uniform value (v_readlane_b32 takes an SGPR index).
__device__ __forceinline__ float readlane_f(float v, int lane) {
    return __uint_as_float(__builtin_amdgcn_readlane(__float_as_uint(v), lane));
}

__device__ __forceinline__ void load_lds16(const void* g, void* l) {
    __builtin_amdgcn_global_load_lds(
        (const __attribute__((address_space(1))) unsigned int*)g,
        (__attribute__((address_space(3))) unsigned int*)l, 16, 0, 0);
}

// ---------------- K1: class stats (8 blocks x 512 thr) ----------------
__global__ __launch_bounds__(512) void k_stats(const float* __restrict__ S,
                                               const int* __restrict__ lab,
                                               float* __restrict__ ws) {
    __shared__ int lb[NS];
    __shared__ float r0[8][64], r1[8][64];
    __shared__ int rc[8];
    int tid = threadIdx.x;
    for (int l = tid; l < NS; l += 512) lb[l] = lab[l];
    __syncthreads();
    int dl = tid & 63, ch = tid >> 6;          // ch 0..7
    int dd = blockIdx.x * 64 + dl;
    float s0 = 0.f, s1 = 0.f;
    int n1 = 0;
    for (int n = ch * 64; n < ch * 64 + 64; ++n) {
        float v = S[n * DF + dd];
        if (lb[n]) { s1 += v; n1++; } else { s0 += v; }
    }
    r0[ch][dl] = s0; r1[ch][dl] = s1;
    if (dl == 0) rc[ch] = n1;
    __syncthreads();
    if (ch == 0) {
        float t0 = 0.f, t1 = 0.f; int n1t = 0;
#pragma unroll
        for (int x = 0; x < 8; ++x) { t0 += r0[x][dl]; t1 += r1[x][dl]; n1t += rc[x]; }
        float fn1 = (float)n1t, fn0 = (float)(NS - n1t);
        ws[WS_MEAN0 + dd] = t0 / fn0;
        ws[WS_MEAN1 + dd] = t1 / fn1;
        ws[WS_MEANA + dd] = (t0 + t1) / (float)NS;
        if (blockIdx.x == 0 && dl == 0) {
            ws[WS_CNT] = fn0; ws[WS_CNT + 1] = fn1;
            ws[WS_KC] = 0.f; ws[WS_KC + 1] = 0.f;
        }
    }
}

// ---------------- K2a: masked partial Grams (K-split x8) ----------------
__global__ __launch_bounds__(256) void k_gram_part(const float* __restrict__ S,
                                                   const int* __restrict__ lab,
                                                   float* __restrict__ ws) {
    __shared__ float SA[16 * 65];
    __shared__ float SB[16 * 65];
    __shared__ int lb[16];
    int tx = threadIdx.x, ty = threadIdx.y;
    int tid = ty * 16 + tx;
    int i0 = blockIdx.x * 64, j0 = blockIdx.y * 64;
    int z = blockIdx.z;
    float a0[4][4] = {{0.f}}, a1[4][4] = {{0.f}};
    for (int nc = z * 64; nc < z * 64 + 64; nc += 16) {
#pragma unroll
        for (int l = 0; l < 4; ++l) {
            int idx = tid + 256 * l;
            int nn = idx >> 6, col = idx & 63;
            SA[nn * 65 + col] = S[(nc + nn) * DF + i0 + col];
            SB[nn * 65 + col] = S[(nc + nn) * DF + j0 + col];
        }
        if (tid < 16) lb[tid] = lab[nc + tid];
        __syncthreads();
#pragma unroll
        for (int kk = 0; kk < 16; ++kk) {
            float av[4], bv[4];
#pragma unroll
            for (int r = 0; r < 4; ++r) av[r] = SA[kk * 65 + ty * 4 + r];
#pragma unroll
            for (int s = 0; s < 4; ++s) bv[s] = SB[kk * 65 + tx * 4 + s];
            if (lb[kk]) {
#pragma unroll
                for (int r = 0; r < 4; ++r)
#pragma unroll
                    for (int s = 0; s < 4; ++s) a1[r][s] += av[r] * bv[s];
            } else {
#pragma unroll
                for (int r = 0; r < 4; ++r)
#pragma unroll
                    for (int s = 0; s < 4; ++s) a0[r][s] += av[r] * bv[s];
            }
        }
        __syncthreads();
    }
    float* Gp = ws + WS_GP;
#pragma unroll
    for (int r = 0; r < 4; ++r) {
        int i = i0 + ty * 4 + r;
#pragma unroll
        for (int s = 0; s < 4; ++s) {
            int j = j0 + tx * 4 + s;
            Gp[((z * 2 + 0) * DF + i) * DF + j] = a0[r][s];
            Gp[((z * 2 + 1) * DF + i) * DF + j] = a1[r][s];
        }
    }
}

// ---------------- K2b: assemble M_c from partials (into A0) ----------------
__global__ __launch_bounds__(256) void k_asm(float* __restrict__ ws) {
    const float* Gp = ws + WS_GP;
    int e = blockIdx.x * 256 + threadIdx.x;   // 0..262143
    int i = e >> 9, j = e & 511;
    float g0 = 0.f, g1 = 0.f;
#pragma unroll
    for (int ch = 0; ch < 8; ++ch) {
        g0 += Gp[((ch * 2 + 0) * DF + i) * DF + j];
        g1 += Gp[((ch * 2 + 1) * DF + i) * DF + j];
    }
    float n0 = ws[WS_CNT], n1 = ws[WS_CNT + 1];
    float lam0 = fminf(n0 / (n0 + 1.f), 0.1f);
    float lam1 = fminf(n1 / (n1 + 1.f), 0.1f);
    float m0i = ws[WS_MEAN0 + i], m1i = ws[WS_MEAN1 + i], mai = ws[WS_MEANA + i];
    float m0j = ws[WS_MEAN0 + j], m1j = ws[WS_MEAN1 + j], maj = ws[WS_MEANA + j];
    float task = (g0 + g1 - (float)NS * mai * maj) / (float)(NS - 1);
    float cov0 = (g0 - n0 * m0i * m0j) / (n0 - 1.f);
    float cov1 = (g1 - n1 * m1i * m1j) / (n1 - 1.f);
    float dg = (i == j) ? 0.1f : 0.f;
    ws[WS_M + i * DF + j] = lam0 * cov0 + (1.f - lam0) * task + dg;
    ws[WS_M + DF * DF + i * DF + j] = lam1 * cov1 + (1.f - lam1) * task + dg;
}

// ---------------- K3: fused Gauss-Jordan step (src -> dst ping-pong) ----------------
// Phase 1 is REGISTER-resident: thread owns col jl rows w*16..w*16+15 in
// Tr[16] (static indices only). Cross-lane: pivot rows via 1 parity LDS
// rbuf/round (1 barrier), pivot cols via readlane with runtime-uniform lane
// (SGPR index). Round loop pinned unroll 1 (auto-unroll = 256-VGPR scratch,
// R6-R8). R10's LDS phase-1 issued ~100 ds_read/thread/round -> LDS-bound.
__global__ __launch_bounds__(256) void k_step(float* __restrict__ ws, int k,
                                              int so, int dofs, int wbf) {
    int c = blockIdx.y;
    int jh = blockIdx.z;
    int ti = blockIdx.x >> 3, tj = blockIdx.x & 7;
    const float* S_ = ws + so + (size_t)c * DF * DF;
    float* D_ = ws + dofs + (size_t)c * DF * DF;
    unsigned short* pb = (unsigned short*)(ws + WS_PB) + (size_t)c * DF * DF;
    __shared__ float T[64 * 65];
    __shared__ float LV[64 * 65];
    __shared__ float LU[64 * 33];
    __shared__ float D1[64 * 33];
    __shared__ float rbuf[2][4][64];
    int tid = threadIdx.x;
    int jl = tid & 63, w = tid >> 6;
    bool isdiag = (ti == k) && (tj == k);
    bool isrow = (ti == k) && (tj != k);
    bool iscol = (tj == k) && (ti != k);

    // phase 0: pivot tile straight into registers; V/U into LDS
    float Tr[16];
    {
        const float* Akk = S_ + (k * 64) * DF + k * 64;
#pragma unroll
        for (int m = 0; m < 16; ++m) Tr[m] = Akk[(w * 16 + m) * DF + jl];
    }
    if (ti != k) {
        const float* src = S_ + (ti * 64) * DF + k * 64;   // V = A[ti][k] (full)
#pragma unroll
        for (int m = 0; m < 16; ++m) {
            int idx = tid + 256 * m;
            int i = idx >> 6, j = idx & 63;
            LV[i * 65 + j] = src[i * DF + j];
        }
    }
    if (tj != k) {
        const float* src = S_ + (k * 64) * DF + tj * 64 + jh * 32;  // U half-cols
#pragma unroll
        for (int m = 0; m < 8; ++m) {
            int idx = tid + 256 * m;
            int i = idx >> 5, j = idx & 31;
            LU[i * 33 + j] = src[i * DF + j];
        }
    }

    // phase 1: 4 pivots/round, 16 rounds, 1 barrier/round (parity rbuf)
#pragma unroll 1
    for (int r = 0; r < 16; ++r) {
        int q0 = r * 4;
        int par = r & 1;
        if (w == (q0 >> 4)) {
            int mb = (r & 3) * 4;   // q0 & 15 (select chain: no dynamic reg idx)
            float t0 = (mb == 0) ? Tr[0] : (mb == 4) ? Tr[4] : (mb == 8) ? Tr[8] : Tr[12];
            float t1 = (mb == 0) ? Tr[1] : (mb == 4) ? Tr[5] : (mb == 8) ? Tr[9] : Tr[13];
            float t2 = (mb == 0) ? Tr[2] : (mb == 4) ? Tr[6] : (mb == 8) ? Tr[10] : Tr[14];
            float t3 = (mb == 0) ? Tr[3] : (mb == 4) ? Tr[7] : (mb == 8) ? Tr[11] : Tr[15];
            rbuf[par][0][jl] = t0;
            rbuf[par][1][jl] = t1;
            rbuf[par][2][jl] = t2;
            rbuf[par][3][jl] = t3;
        }
        __syncthreads();
        // 4x4 pivot block (broadcast LDS reads), inverted redundantly
        float B[4][4];
#pragma unroll
        for (int a = 0; a < 4; ++a)
#pragma unroll
            for (int b = 0; b < 4; ++b) B[a][b] = rbuf[par][a][q0 + b];
#pragma unroll
        for (int p = 0; p < 4; ++p) {
            float piv = 1.0f / B[p][p];
#pragma unroll
            for (int j = 0; j < 4; ++j) if (j != p) B[p][j] *= piv;
#pragma unroll
            for (int i2 = 0; i2 < 4; ++i2) if (i2 != p) {
                float f = B[i2][p];
#pragma unroll
                for (int j = 0; j < 4; ++j) if (j != p) B[i2][j] -= f * B[p][j];
                B[i2][p] = -f * piv;
            }
            B[p][p] = piv;
        }
        float Rv0 = rbuf[par][0][jl];
        float Rv1 = rbuf[par][1][jl];
        float Rv2 = rbuf[par][2][jl];
        float Rv3 = rbuf[par][3][jl];
        float nr[4];
#pragma unroll
        for (int a = 0; a < 4; ++a)
            nr[a] = B[a][0] * Rv0 + B[a][1] * Rv1 + B[a][2] * Rv2 + B[a][3] * Rv3;
        int bsel = jl - q0;
        bool colin = (unsigned)bsel < 4u;
        float Bc[4];
#pragma unroll
        for (int a = 0; a < 4; ++a)
            Bc[a] = (bsel == 0) ? B[a][0] : (bsel == 1) ? B[a][1]
                  : (bsel == 2) ? B[a][2] : B[a][3];
#pragma unroll
        for (int m = 0; m < 16; ++m) {
            int i = w * 16 + m;
            // pivot-col values: intra-wave readlane (lane = q0+a, uniform)
            float c0 = readlane_f(Tr[m], q0 + 0);
            float c1 = readlane_f(Tr[m], q0 + 1);
            float c2 = readlane_f(Tr[m], q0 + 2);
            float c3 = readlane_f(Tr[m], q0 + 3);
            float tv = Tr[m];
            float g = tv - (c0 * nr[0] + c1 * nr[1] + c2 * nr[2] + c3 * nr[3]);
            int rsel = i - q0;
            bool rowin = (unsigned)rsel < 4u;
            if (rowin)
                g = (rsel == 0) ? nr[0] : (rsel == 1) ? nr[1]
                  : (rsel == 2) ? nr[2] : nr[3];
            if (colin) {
                float gc;
                if (rowin)
                    gc = (rsel == 0) ? Bc[0] : (rsel == 1) ? Bc[1]
                       : (rsel == 2) ? Bc[2] : Bc[3];
                else
                    gc = -(c0 * Bc[0] + c1 * Bc[1] + c2 * Bc[2] + c3 * Bc[3]);
                g = gc;
            }
            Tr[m] = g;
        }
    }
    // publish inverted pivot to LDS for phase 2
#pragma unroll
    for (int m = 0; m < 16; ++m) T[(w * 16 + m) * 65 + jl] = Tr[m];
    __syncthreads();

    // phase 2: col-half tile update (read src, write dst)
    int tx8 = tid & 7, ty32 = tid >> 3;
    int cb0 = jh * 32;
    if (isdiag) {
        float* dst = D_ + (k * 64) * DF + k * 64;
#pragma unroll
        for (int m = 0; m < 8; ++m) {
            int idx = tid + 256 * m;
            int i = idx >> 5, j = idx & 31;
            float v = T[i * 65 + cb0 + j];
            dst[i * DF + cb0 + j] = v;
            if (wbf) pb[(size_t)(k * 64 + i) * DF + k * 64 + cb0 + j] = f2bf(v);
        }
    } else if (isrow) {
        float acc[2][4] = {{0.f}};
#pragma unroll 4
        for (int kk = 0; kk < 64; ++kk) {
            float av[2], bv[4];
#pragma unroll
            for (int r = 0; r < 2; ++r) av[r] = T[(ty32 * 2 + r) * 65 + kk];
#pragma unroll
            for (int s = 0; s < 4; ++s) bv[s] = LU[kk * 33 + tx8 * 4 + s];
#pragma unroll
            for (int r = 0; r < 2; ++r)
#pragma unroll
                for (int s = 0; s < 4; ++s) acc[r][s] += av[r] * bv[s];
        }
        float* dst = D_ + (k * 64) * DF + tj * 64 + cb0;
#pragma unroll
        for (int r = 0; r < 2; ++r)
#pragma unroll
            for (int s = 0; s < 4; ++s) {
                float v = acc[r][s];
                dst[(ty32 * 2 + r) * DF + tx8 * 4 + s] = v;
                if (wbf) pb[(size_t)(k * 64 + ty32 * 2 + r) * DF + tj * 64 + cb0 + tx8 * 4 + s] = f2bf(v);
            }
    } else if (iscol) {
        float acc[2][4] = {{0.f}};
#pragma unroll 4
        for (int kk = 0; kk < 64; ++kk) {
            float av[2], bv[4];
#pragma unroll
            for (int r = 0; r < 2; ++r) av[r] = LV[(ty32 * 2 + r) * 65 + kk];
#pragma unroll
            for (int s = 0; s < 4; ++s) bv[s] = T[kk * 65 + cb0 + tx8 * 4 + s];
#pragma unroll
            for (int r = 0; r < 2; ++r)
#pragma unroll
                for (int s = 0; s < 4; ++s) acc[r][s] += av[r] * bv[s];
        }
        float* dst = D_ + (ti * 64) * DF + k * 64 + cb0;
#pragma unroll
        for (int r = 0; r < 2; ++r)
#pragma unroll
            for (int s = 0; s < 4; ++s) {
                float v = -acc[r][s];
                dst[(ty32 * 2 + r) * DF + tx8 * 4 + s] = v;
                if (wbf) pb[(size_t)(ti * 64 + ty32 * 2 + r) * DF + k * 64 + cb0 + tx8 * 4 + s] = f2bf(v);
            }
    } else {
        // interior: out = Y_half - V*(P*U_half)
        float a1[2][4] = {{0.f}};
#pragma unroll 4
        for (int kk = 0; kk < 64; ++kk) {
            float av[2], bv[4];
#pragma unroll
            for (int r = 0; r < 2; ++r) av[r] = T[(ty32 * 2 + r) * 65 + kk];
#pragma unroll
            for (int s = 0; s < 4; ++s) bv[s] = LU[kk * 33 + tx8 * 4 + s];
#pragma unroll
            for (int r = 0; r < 2; ++r)
#pragma unroll
                for (int s = 0; s < 4; ++s) a1[r][s] += av[r] * bv[s];
        }
        __syncthreads();
#pragma unroll
        for (int r = 0; r < 2; ++r)
#pragma unroll
            for (int s = 0; s < 4; ++s) D1[(ty32 * 2 + r) * 33 + tx8 * 4 + s] = a1[r][s];
        __syncthreads();
        float a2[2][4] = {{0.f}};
#pragma unroll 4
        for (int kk = 0; kk < 64; ++kk) {
            float av[2], bv[4];
#pragma unroll
            for (int r = 0; r < 2; ++r) av[r] = LV[(ty32 * 2 + r) * 65 + kk];
#pragma unroll
            for (int s = 0; s < 4; ++s) bv[s] = D1[kk * 33 + tx8 * 4 + s];
#pragma unroll
            for (int r = 0; r < 2; ++r)
#pragma unroll
                for (int s = 0; s < 4; ++s) a2[r][s] += av[r] * bv[s];
        }
        const float* Ys = S_ + (ti * 64) * DF + tj * 64 + cb0;
        float* dst = D_ + (ti * 64) * DF + tj * 64 + cb0;
#pragma unroll
        for (int r = 0; r < 2; ++r)
#pragma unroll
            for (int s = 0; s < 4; ++s) {
                int off = (ty32 * 2 + r) * DF + tx8 * 4 + s;
                float nv2 = Ys[off] - a2[r][s];
                dst[off] = nv2;
                if (wbf) pb[(size_t)(ti * 64 + ty32 * 2 + r) * DF + tj * 64 + cb0 + tx8 * 4 + s] = f2bf(nv2);
            }
    }
}

// ---------------- K4: v_c = P_c m_c, k_c = m^T v ----------------
__global__ __launch_bounds__(256) void k_vk(float* __restrict__ ws) {
    int c = blockIdx.x >> 3, rb = blockIdx.x & 7;
    const float* P = ws + WS_M + c * DF * DF;
    const float* mc = ws + (c ? WS_MEAN1 : WS_MEAN0);
    float* v = ws + (c ? WS_V1 : WS_V0);
    __shared__ float ml[DF];
    __shared__ float red[4][64];
    int tid = threadIdx.x;
    for (int l = tid; l < DF; l += 256) ml[l] = mc[l];
    __syncthreads();
    int rl = tid & 63, ch = tid >> 6;
    int row = rb * 64 + rl;
    float dot = 0.f;
    const float* pr = P + (size_t)row * DF + ch * 128;
#pragma unroll 4
    for (int t = 0; t < 32; ++t) {
        float4 pv = *(const float4*)(pr + t * 4);
        const float* mm = ml + ch * 128 + t * 4;
        dot += pv.x * mm[0] + pv.y * mm[1] + pv.z * mm[2] + pv.w * mm[3];
    }
    red[ch][rl] = dot;
    __syncthreads();
    if (ch == 0) {
        float d = red[0][rl] + red[1][rl] + red[2][rl] + red[3][rl];
        v[row] = d;
        float kp = d * ml[row];
#pragma unroll
        for (int off = 32; off > 0; off >>= 1) kp += __shfl_down(kp, off);
        if (rl == 0) atomicAdd(&ws[WS_KC + c], kp);
    }
}

// ---------------- K5: fused Q->bf16 + logits init ----------------
__global__ __launch_bounds__(256) void k_qinit(const float* __restrict__ Q,
                                               float* __restrict__ ws,
                                               float* __restrict__ out) {
    unsigned short* qbw = (unsigned short*)(ws + WS_QB);
    const float* v0 = ws + WS_V0;
    const float* v1 = ws + WS_V1;
    int lane = threadIdx.x & 63;
    int q = blockIdx.x * 4 + (threadIdx.x >> 6);
    const float* qrow = Q + (size_t)q * DF + lane * 8;
    float4 x0 = *(const float4*)(qrow);
    float4 x1 = *(const float4*)(qrow + 4);
    const float* v0p = v0 + lane * 8;
    const float* v1p = v1 + lane * 8;
    float4 w00 = *(const float4*)(v0p), w01 = *(const float4*)(v0p + 4);
    float4 w10 = *(const float4*)(v1p), w11 = *(const float4*)(v1p + 4);
    float a0 = x0.x * w00.x + x0.y * w00.y + x0.z * w00.z + x0.w * w00.w
             + x1.x * w01.x + x1.y * w01.y + x1.z * w01.z + x1.w * w01.w;
    float a1 = x0.x * w10.x + x0.y * w10.y + x0.z * w10.z + x0.w * w10.w
             + x1.x * w11.x + x1.y * w11.y + x1.z * w11.z + x1.w * w11.w;
    short8 r;
    r[0] = (short)f2bf(x0.x); r[1] = (short)f2bf(x0.y);
    r[2] = (short)f2bf(x0.z); r[3] = (short)f2bf(x0.w);
    r[4] = (short)f2bf(x1.x); r[5] = (short)f2bf(x1.y);
    r[6] = (short)f2bf(x1.z); r[7] = (short)f2bf(x1.w);
    *(short8*)(qbw + (size_t)q * DF + lane * 8) = r;
#pragma unroll
    for (int off = 32; off > 0; off >>= 1) {
        a0 += __shfl_down(a0, off);
        a1 += __shfl_down(a1, off);
    }
    if (lane == 0) {
        out[q * 2 + 0] = 2.f * a0 - ws[WS_KC + 0];
        out[q * 2 + 1] = 2.f * a1 - ws[WS_KC + 1];
    }
}

// ---------------- K6: MFMA GEMM, 128x128 tile, LDS staging + swizzle ----------------
__global__ __launch_bounds__(256, 3) void k_gemm(const float* __restrict__ ws,
                                                 float* __restrict__ out) {
    const unsigned short* qb = (const unsigned short*)(ws + WS_QB);
    int c = blockIdx.y >> 2;
    int n0 = (blockIdx.y & 3) * 128;
    const unsigned short* pbc = (const unsigned short*)(ws + WS_PB) + (size_t)c * DF * DF;
    int q0 = blockIdx.x * 128;
    __shared__ __align__(16) unsigned short Abuf[128 * 64];   // 16 KB
    __shared__ __align__(16) unsigned short Bbuf[128 * 64];   // 16 KB
    int tid = threadIdx.x;
    int w = tid >> 6, lane = tid & 63;
    int quad = lane >> 4, l15 = lane & 15;
    floatx4 acc[2][8];
#pragma unroll
    for (int mt = 0; mt < 2; ++mt)
#pragma unroll
        for (int nt = 0; nt < 8; ++nt) acc[mt][nt] = (floatx4)(0.f);

    for (int kt = 0; kt < 8; ++kt) {
        int kc = kt * 64;
#pragma unroll
        for (int i = 0; i < 4; ++i) {
            int o = tid * 16 + i * 4096;
            int row = o >> 7;
            int sg = ((o >> 4) & 7) ^ (row & 7);
            load_lds16(qb + (size_t)(q0 + row) * DF + kc + sg * 8, (char*)Abuf + o);
        }
#pragma unroll
        for (int i = 0; i < 4; ++i) {
            int o = tid * 16 + i * 4096;
            int row = o >> 7;
            int sg = ((o >> 4) & 7) ^ (row & 7);
            load_lds16(pbc + (size_t)(n0 + row) * DF + kc + sg * 8, (char*)Bbuf + o);
        }
        __syncthreads();
#pragma unroll
        for (int kk2 = 0; kk2 < 2; ++kk2) {
            int u = ((kk2 * 4 + quad) ^ (l15 & 7)) << 4;
            short8 b[8];
#pragma unroll
            for (int nt = 0; nt < 8; ++nt)
                b[nt] = *(const short8*)((const char*)Bbuf + (nt * 16 + l15) * 128 + u);
#pragma unroll
            for (int mt = 0; mt < 2; ++mt) {
                short8 a = *(const short8*)((const char*)Abuf + (w * 32 + mt * 16 + l15) * 128 + u);
#pragma unroll
                for (int nt = 0; nt < 8; ++nt)
                    acc[mt][nt] = __builtin_amdgcn_mfma_f32_16x16x32_bf16(a, b[nt], acc[mt][nt], 0, 0, 0);
            }
        }
        __syncthreads();
    }
#pragma unroll
    for (int mt = 0; mt < 2; ++mt)
#pragma unroll
        for (int reg = 0; reg < 4; ++reg) {
            int row = w * 32 + mt * 16 + quad * 4 + reg;
            float part = 0.f;
#pragma unroll
            for (int nt = 0; nt < 8; ++nt) {
                float h = acc[mt][nt][reg];
                unsigned qu = qb[(size_t)(q0 + row) * DF + n0 + nt * 16 + l15];
                part += h * __uint_as_float(qu << 16);
            }
            part += __shfl_xor(part, 1);
            part += __shfl_xor(part, 2);
            part += __shfl_xor(part, 4);
            part += __shfl_xor(part, 8);
            if (l15 == 0) atomicAdd(&out[(size_t)(q0 + row) * 2 + c], -part);
        }
}

extern "C" void kernel_launch(void* const* d_in, const int* in_sizes, int n_in,
                              void* d_out, int out_size, void* d_ws, size_t ws_size,
                              hipStream_t stream) {
    const float* S = (const float*)d_in[0];
    const int* lab = (const int*)d_in[1];
    const float* Q = (const float*)d_in[2];
    float* out = (float*)d_out;
    float* ws = (float*)d_ws;

    k_stats<<<8, 512, 0, stream>>>(S, lab, ws);
    k_gram_part<<<dim3(8, 8, 8), dim3(16, 16), 0, stream>>>(S, lab, ws);
    k_asm<<<1024, 256, 0, stream>>>(ws);
    int so = WS_M, dofs = WS_A1;
    for (int k = 0; k < 8; ++k) {
        k_step<<<dim3(64, 2, 2), 256, 0, stream>>>(ws, k, so, dofs, k == 7 ? 1 : 0);
        int t = so; so = dofs; dofs = t;
    }
    // after 8 swaps the final matrix lands back in WS_M
    k_vk<<<16, 256, 0, stream>>>(ws);
    k_qinit<<<NQ / 4, 256, 0, stream>>>(Q, ws, out);
    k_gemm<<<dim3(NQ / 128, 8), 256, 0, stream>>>(ws, out);
}